// Round 9
// baseline (78.225 us; speedup 1.0000x reference)
//
#include <hip/hip_runtime.h>
#include <math.h>

#define NB     512
#define NV     6890
#define NF     13776
#define NVHD   20000
#define NPARTS 10
#define NTHREADS 1024
#define NWAVES (NTHREADS/64)
#define CUT    6698             // verts >= CUT (192, contiguous tail) read from global (L2-hot)
#define NCHF   ((NF + 63) / 64) // 216 chunks for the face sort

// ---- S: deterministic 1-block counting sort of faces by part (stable, no atomics) ----
__global__ __launch_bounds__(1024) void sort_faces(
    const int* __restrict__ faces,
    const int* __restrict__ part_fid,
    uint2*     __restrict__ f_sorted)   // [NF] {i0|i1<<16, i2|p<<16}, part-sorted
{
    __shared__ unsigned chunkoff[NPARTS][NCHF];   // 8640 B
    __shared__ unsigned pbase[NPARTS];
    const int tid = threadIdx.x, wave = tid >> 6, lane = tid & 63;
    const unsigned long long lowmask = (1ull << lane) - 1ull;

    for (int k = tid; k < NPARTS * NCHF; k += 1024) (&chunkoff[0][0])[k] = 0u;
    __syncthreads();

    // per-chunk per-part counts via ballot match
    for (int c = wave; c < NCHF; c += NWAVES) {
        int i = c * 64 + lane;
        bool valid = i < NF;
        unsigned p = valid ? (unsigned)part_fid[i] : 0u;
        unsigned long long m = ~0ull;
        #pragma unroll
        for (int b = 0; b < 4; b++) {
            unsigned long long bb = __ballot(valid && ((p >> b) & 1u));
            m &= ((p >> b) & 1u) ? bb : ~bb;
        }
        m &= __ballot(valid);
        if (valid && (m & lowmask) == 0ull)
            chunkoff[p][c] = (unsigned)__popcll(m);
    }
    __syncthreads();

    // exclusive scan of each part row (wave r owns row r)
    if (wave < NPARTS) {
        unsigned carry = 0;
        #pragma unroll
        for (int seg = 0; seg < (NCHF + 63) / 64; seg++) {
            int idx = seg * 64 + lane;
            unsigned v = (idx < NCHF) ? chunkoff[wave][idx] : 0u;
            unsigned incl = v;
            #pragma unroll
            for (int off = 1; off < 64; off <<= 1) {
                unsigned n = __shfl_up(incl, off, 64);
                if (lane >= off) incl += n;
            }
            if (idx < NCHF) chunkoff[wave][idx] = incl - v + carry;
            carry += __shfl(incl, 63, 64);
        }
        if (lane == 0) pbase[wave] = carry;
    }
    __syncthreads();
    if (tid == 0) {
        unsigned r = 0;
        #pragma unroll
        for (int p = 0; p < NPARTS; p++) { unsigned t = pbase[p]; pbase[p] = r; r += t; }
    }
    __syncthreads();

    // stable scatter (packs face + part)
    for (int c = wave; c < NCHF; c += NWAVES) {
        int i = c * 64 + lane;
        bool valid = i < NF;
        unsigned p = valid ? (unsigned)part_fid[i] : 0u;
        unsigned long long m = ~0ull;
        #pragma unroll
        for (int b = 0; b < 4; b++) {
            unsigned long long bb = __ballot(valid && ((p >> b) & 1u));
            m &= ((p >> b) & 1u) ? bb : ~bb;
        }
        m &= __ballot(valid);
        if (valid) {
            unsigned rank = (unsigned)__popcll(m & lowmask);
            unsigned pos = pbase[p] + chunkoff[p][c] + rank;
            f_sorted[pos] = make_uint2(
                (unsigned)faces[3*i+0] | ((unsigned)faces[3*i+1] << 16),
                (unsigned)faces[3*i+2] | (p << 16));
        }
    }
}

// ---- Precompute HD table (batch-independent) ----
__global__ void build_tables(const float* __restrict__ bary,
                             const int*   __restrict__ faces,
                             const int*   __restrict__ hd_fid,
                             const int*   __restrict__ part_fid,
                             uint4* __restrict__ hd_pack)   // [NVHD]{i0|i1<<16, i2|p<<16, w0, w1}
{
    int i = blockIdx.x * blockDim.x + threadIdx.x;
    if (i < NVHD) {
        int fid = hd_fid[i];
        float b0 = bary[3*i+0], b1 = bary[3*i+1], b2 = bary[3*i+2];
        float inv = 1.0f / (b0 + b1 + b2);
        hd_pack[i] = make_uint4((unsigned)faces[3*fid+0] | ((unsigned)faces[3*fid+1] << 16),
                                (unsigned)faces[3*fid+2] | ((unsigned)part_fid[fid] << 16),
                                __float_as_uint(b0*inv), __float_as_uint(b1*inv));
    }
}

__global__ __launch_bounds__(NTHREADS, 8) void stab_kernel(
    const float* __restrict__ vertices,   // [B][V][3] f32
    const uint2* __restrict__ f_pack,     // [NF] part-sorted
    const uint4* __restrict__ hd_pack,    // [NVHD]
    float*       __restrict__ out)        // [B]
{
    __shared__ float2 sxy[CUT];              // 53584 B
    __shared__ float  szz[CUT];              // 26792 B
    __shared__ float  spart[NPARTS];         // 40 B
    __shared__ float  sredp[NWAVES][NPARTS]; // 640 B  (total 81056 <= 81920 -> 2 blocks/CU)

    const int tid  = threadIdx.x;
    const int b    = blockIdx.x;
    const int wave = tid >> 6;
    const int lane = tid & 63;
    const float* __restrict__ vb = vertices + (size_t)b * (NV * 3);

    // ---- Phase A: stage first CUT vertices into LDS ----
    for (int v = tid; v < CUT; v += NTHREADS) {
        float x = vb[3 * v + 0];
        float y = vb[3 * v + 1];
        float z = vb[3 * v + 2];
        sxy[v] = make_float2(x, y);
        szz[v] = z;
    }
    __syncthreads();

#define GETV(idx, X, Y, Z) do {                                     \
        int _s = (idx); int _c = _s < CUT ? _s : CUT - 1;           \
        float2 _t = sxy[_c]; float _z = szz[_c];                    \
        X = _t.x; Y = _t.y; Z = _z;                                 \
        if (_s >= CUT) {                                            \
            X = vb[3*_s+0]; Y = vb[3*_s+1]; Z = vb[3*_s+2];         \
        }                                                           \
    } while (0)

    // ---- Phase B: per-face signed volumes -> per-part sums ----
    // faces are part-sorted: p is wave-uniform on ~96% of iterations
    float accp[NPARTS];
    #pragma unroll
    for (int q = 0; q < NPARTS; q++) accp[q] = 0.f;

    #pragma unroll 2
    for (int f = tid; f < NF; f += NTHREADS) {
        uint2 ft = f_pack[f];
        int i0 = ft.x & 0xFFFF, i1 = ft.x >> 16;
        int i2 = ft.y & 0xFFFF, p  = (int)(ft.y >> 16);
        float x0, y0, z0, x1, y1, z1, x2, y2, z2;
        GETV(i0, x0, y0, z0);
        GETV(i1, x1, y1, z1);
        GETV(i2, x2, y2, z2);
        float cx = y0 * z1 - z0 * y1;
        float cy = z0 * x1 - x0 * z1;
        float cz = x0 * y1 - y0 * x1;
        float vol = (cx * x2 + cy * y2 + cz * z2) * (1.0f / 6.0f);
        int pu = __builtin_amdgcn_readfirstlane(p);
        if (__all(p == pu)) {
            switch (pu) {                      // wave-uniform SALU branch, 1 VALU add
                case 0: accp[0] += vol; break;
                case 1: accp[1] += vol; break;
                case 2: accp[2] += vol; break;
                case 3: accp[3] += vol; break;
                case 4: accp[4] += vol; break;
                case 5: accp[5] += vol; break;
                case 6: accp[6] += vol; break;
                case 7: accp[7] += vol; break;
                case 8: accp[8] += vol; break;
                default: accp[9] += vol; break;
            }
        } else {                               // rare bin-boundary iteration
            #pragma unroll
            for (int q = 0; q < NPARTS; q++) accp[q] += (p == q) ? vol : 0.f;
        }
    }
    #pragma unroll
    for (int q = 0; q < NPARTS; q++) {
        float s = accp[q];
        #pragma unroll
        for (int off = 32; off > 0; off >>= 1) s += __shfl_down(s, off, 64);
        accp[q] = s;
    }
    if (lane == 0) {
        #pragma unroll
        for (int q = 0; q < NPARTS; q++) sredp[wave][q] = accp[q];
    }
    __syncthreads();
    if (tid < NPARTS) {
        float s = 0.f;
        #pragma unroll
        for (int w = 0; w < NWAVES; w++) s += sredp[w][tid];
        spart[tid] = s;
    }
    __syncthreads();

    // ---- Phase C: HD vertices; y-moments dropped (output needs only x,z) ----
    float sVx = 0.f, sVz = 0.f, sVol = 0.f;
    float sPx = 0.f, sPz = 0.f, sPw  = 0.f;

    #pragma unroll 4
    for (int v = tid; v < NVHD; v += NTHREADS) {
        uint4 hp = hd_pack[v];
        int i0 = hp.x & 0xFFFF, i1 = hp.x >> 16;
        int i2 = hp.y & 0xFFFF, p  = hp.y >> 16;
        float w0 = __uint_as_float(hp.z);
        float w1 = __uint_as_float(hp.w);
        float w2 = 1.0f - w0 - w1;
        float x0, y0, z0, x1, y1, z1, x2, y2, z2;
        GETV(i0, x0, y0, z0);
        GETV(i1, x1, y1, z1);
        GETV(i2, x2, y2, z2);
        float x = w0 * x0 + w1 * x1 + w2 * x2;
        float y = w0 * y0 + w1 * y1 + w2 * y2;
        float z = w0 * z0 + w1 * z1 + w2 * z2;
        float vol = spart[p];
        float pw  = (y < 0.f) ? fmaf(-100.f, y, 1.f) : __expf(-10.f * y);
        sVx += x * vol;  sVz += z * vol;  sVol += vol;
        sPx += x * pw;   sPz += z * pw;   sPw  += pw;
    }

    float vals[6] = {sVx, sVz, sVol, sPx, sPz, sPw};
    #pragma unroll
    for (int q = 0; q < 6; q++) {
        float s = vals[q];
        #pragma unroll
        for (int off = 32; off > 0; off >>= 1) s += __shfl_down(s, off, 64);
        vals[q] = s;
    }
    float* sred6 = &sredp[0][0];   // reuse (dead after spart): 16*6*4 = 384 B <= 640 B
    if (lane == 0) {
        #pragma unroll
        for (int q = 0; q < 6; q++) sred6[wave * 6 + q] = vals[q];
    }
    __syncthreads();
    if (tid == 0) {
        float r[6];
        #pragma unroll
        for (int q = 0; q < 6; q++) {
            float s = 0.f;
            #pragma unroll
            for (int w = 0; w < NWAVES; w++) s += sred6[w * 6 + q];
            r[q] = s;
        }
        float invVol = 1.0f / r[2];
        float invPw  = 1.0f / (r[5] + 1e-6f);
        float comx = r[0] * invVol, comz = r[1] * invVol;
        float copx = r[3] * invPw,  copz = r[4] * invPw;
        float d0 = comx - copx, d2 = comz - copz;
        out[b] = sqrtf(d0 * d0 + d2 * d2);
    }
#undef GETV
}

extern "C" void kernel_launch(void* const* d_in, const int* in_sizes, int n_in,
                              void* d_out, int out_size, void* d_ws, size_t ws_size,
                              hipStream_t stream) {
    const float* vertices = (const float*)d_in[0];
    const float* bary     = (const float*)d_in[1];
    const int*   faces    = (const int*)d_in[2];
    const int*   hd_fid   = (const int*)d_in[3];
    const int*   part_fid = (const int*)d_in[4];
    float* out = (float*)d_out;

    char* ws = (char*)d_ws;
    uint2* f_pack  = (uint2*)ws;                          // NF*8 = 110208 (16B-aligned)
    uint4* hd_pack = (uint4*)(ws + (size_t)NF * 8);       // NVHD*16

    sort_faces<<<1, 1024, 0, stream>>>(faces, part_fid, f_pack);
    build_tables<<<(NVHD + 255) / 256, 256, 0, stream>>>(bary, faces, hd_fid, part_fid, hd_pack);
    stab_kernel<<<NB, NTHREADS, 0, stream>>>(vertices, f_pack, hd_pack, out);
}

// Round 10
// 65.689 us; speedup vs baseline: 1.1908x; 1.1908x over previous
//
#include <hip/hip_runtime.h>
#include <math.h>

#define NB     512
#define NV     6890
#define NF     13776
#define NVHD   20000
#define NPARTS 10
#define NTHREADS 1024
#define NWAVES (NTHREADS/64)
#define CUT    6697              // verts < CUT live in LDS; slot CUT = dummy
#define NCHF   ((NF + 63) / 64)    // 216
#define NCHH   ((NVHD + 63) / 64)  // 313

// ---- K1: build packed tables with ORIGINAL indices (batch-independent) ----
__global__ void build_tables(const float* __restrict__ bary,
                             const int*   __restrict__ faces,
                             const int*   __restrict__ hd_fid,
                             const int*   __restrict__ part_fid,
                             uint2* __restrict__ f_pack,    // [NF]  {i0|i1<<16, i2|p<<16}
                             uint4* __restrict__ hd_pack)   // [NVHD]{i0|i1<<16, i2|p<<16, w0, w1}
{
    int i = blockIdx.x * blockDim.x + threadIdx.x;
    if (i < NF) {
        f_pack[i] = make_uint2((unsigned)faces[3*i+0] | ((unsigned)faces[3*i+1] << 16),
                               (unsigned)faces[3*i+2] | ((unsigned)part_fid[i]  << 16));
    }
    if (i < NVHD) {
        int fid = hd_fid[i];
        float b0 = bary[3*i+0], b1 = bary[3*i+1], b2 = bary[3*i+2];
        float inv = 1.0f / (b0 + b1 + b2);
        hd_pack[i] = make_uint4((unsigned)faces[3*fid+0] | ((unsigned)faces[3*fid+1] << 16),
                                (unsigned)faces[3*fid+2] | ((unsigned)part_fid[fid] << 16),
                                __float_as_uint(b0*inv), __float_as_uint(b1*inv));
    }
}

// ---- K2: deterministic split: entries touching verts >= CUT -> overflow list;
//          neutralize them in the main tables. block 0: faces, block 1: HD. ----
__global__ __launch_bounds__(1024) void split_overflow(
    uint2* __restrict__ f_pack, uint4* __restrict__ hd_pack,
    uint2* __restrict__ ovf_f,  uint4* __restrict__ ovf_h,
    int*   __restrict__ counts)
{
    __shared__ int cnt[NCHH];     // max(NCHF, NCHH)
    const int tid = threadIdx.x, wave = tid >> 6, lane = tid & 63;
    const unsigned long long lowmask = (1ull << lane) - 1ull;

    if (blockIdx.x == 0) {
        for (int c = wave; c < NCHF; c += NWAVES) {
            int i = c * 64 + lane;
            bool bad = false;
            if (i < NF) {
                uint2 ft = f_pack[i];
                bad = ((ft.x & 0xFFFFu) >= CUT) || ((ft.x >> 16) >= CUT) || ((ft.y & 0xFFFFu) >= CUT);
            }
            unsigned long long m = __ballot(bad);
            if (lane == 0) cnt[c] = (int)__popcll(m);
        }
        __syncthreads();
        if (wave == 0) {
            int carry = 0;
            #pragma unroll
            for (int seg = 0; seg < (NCHF + 63) / 64; seg++) {
                int idx = seg * 64 + lane;
                int v = (idx < NCHF) ? cnt[idx] : 0;
                int incl = v;
                #pragma unroll
                for (int off = 1; off < 64; off <<= 1) { int n = __shfl_up(incl, off, 64); if (lane >= off) incl += n; }
                if (idx < NCHF) cnt[idx] = incl - v + carry;
                carry += __shfl(incl, 63, 64);
            }
            if (lane == 0) counts[0] = carry;
        }
        __syncthreads();
        for (int c = wave; c < NCHF; c += NWAVES) {
            int i = c * 64 + lane;
            bool valid = i < NF;
            uint2 ft = valid ? f_pack[i] : make_uint2(0u, 0u);
            bool bad = valid && (((ft.x & 0xFFFFu) >= CUT) || ((ft.x >> 16) >= CUT) || ((ft.y & 0xFFFFu) >= CUT));
            unsigned long long m = __ballot(bad);
            if (bad) {
                int rank = (int)__popcll(m & lowmask);
                ovf_f[cnt[c] + rank] = ft;
                // degenerate face (all corners = dummy) -> vol = 0 exactly
                f_pack[i] = make_uint2((unsigned)CUT | ((unsigned)CUT << 16), (unsigned)CUT);
            }
        }
    } else {
        for (int c = wave; c < NCHH; c += NWAVES) {
            int i = c * 64 + lane;
            bool bad = false;
            if (i < NVHD) {
                uint4 hp = hd_pack[i];
                bad = ((hp.x & 0xFFFFu) >= CUT) || ((hp.x >> 16) >= CUT) || ((hp.y & 0xFFFFu) >= CUT);
            }
            unsigned long long m = __ballot(bad);
            if (lane == 0) cnt[c] = (int)__popcll(m);
        }
        __syncthreads();
        if (wave == 0) {
            int carry = 0;
            #pragma unroll
            for (int seg = 0; seg < (NCHH + 63) / 64; seg++) {
                int idx = seg * 64 + lane;
                int v = (idx < NCHH) ? cnt[idx] : 0;
                int incl = v;
                #pragma unroll
                for (int off = 1; off < 64; off <<= 1) { int n = __shfl_up(incl, off, 64); if (lane >= off) incl += n; }
                if (idx < NCHH) cnt[idx] = incl - v + carry;
                carry += __shfl(incl, 63, 64);
            }
            if (lane == 0) counts[1] = carry;
        }
        __syncthreads();
        for (int c = wave; c < NCHH; c += NWAVES) {
            int i = c * 64 + lane;
            bool valid = i < NVHD;
            uint4 hp = valid ? hd_pack[i] : make_uint4(0u, 0u, 0u, 0u);
            bool bad = valid && (((hp.x & 0xFFFFu) >= CUT) || ((hp.x >> 16) >= CUT) || ((hp.y & 0xFFFFu) >= CUT));
            unsigned long long m = __ballot(bad);
            if (bad) {
                int rank = (int)__popcll(m & lowmask);
                ovf_h[cnt[c] + rank] = hp;
                // dummy corners (y=100 -> pw=exp(-1000)=+0), p=NPARTS -> vol=spart[10]=0
                hd_pack[i] = make_uint4((unsigned)CUT | ((unsigned)CUT << 16),
                                        (unsigned)CUT | ((unsigned)NPARTS << 16),
                                        0u, 0u);   // w0=w1=0 -> w2=1 -> picks dummy corner2
            }
        }
    }
}

__global__ __launch_bounds__(NTHREADS, 8) void stab_kernel(
    const float* __restrict__ vertices,   // [B][V][3] f32
    const uint2* __restrict__ f_pack,     // [NF] clean (all idx <= CUT)
    const uint4* __restrict__ hd_pack,    // [NVHD] clean
    const uint2* __restrict__ ovf_f,      // [counts[0]] original entries
    const uint4* __restrict__ ovf_h,      // [counts[1]]
    const int*   __restrict__ counts,
    float*       __restrict__ out)        // [B]
{
    __shared__ float2 sxy[CUT + 1];            // 53584 B
    __shared__ float  szz[CUT + 1];            // 26792 B
    __shared__ float  spart[NPARTS + 1];       // 44 B  (spart[10] = 0)
    __shared__ float  sredp[NWAVES][NPARTS];   // 640 B   -> total ~81060 (2 blocks/CU)

    const int tid  = threadIdx.x;
    const int b    = blockIdx.x;
    const int wave = tid >> 6;
    const int lane = tid & 63;
    const float* __restrict__ vb = vertices + (size_t)b * (NV * 3);

    // ---- Phase A: stage verts [0,CUT) + dummy slot ----
    for (int v = tid; v < CUT; v += NTHREADS) {
        float x = vb[3 * v + 0];
        float y = vb[3 * v + 1];
        float z = vb[3 * v + 2];
        sxy[v] = make_float2(x, y);
        szz[v] = z;
    }
    if (tid == 0) { sxy[CUT] = make_float2(0.f, 100.f); szz[CUT] = 0.f; }
    __syncthreads();

    // ---- Phase B: clean faces, pure-LDS, branch-free ----
    float accp[NPARTS];
    #pragma unroll
    for (int q = 0; q < NPARTS; q++) accp[q] = 0.f;

    #pragma unroll 2
    for (int f = tid; f < NF; f += NTHREADS) {
        uint2 ft = f_pack[f];
        int i0 = ft.x & 0xFFFF, i1 = ft.x >> 16;
        int i2 = ft.y & 0xFFFF, p  = (int)(ft.y >> 16);
        float2 t0 = sxy[i0]; float z0 = szz[i0];
        float2 t1 = sxy[i1]; float z1 = szz[i1];
        float2 t2 = sxy[i2]; float z2 = szz[i2];
        float cx = t0.y * z1   - z0   * t1.y;
        float cy = z0   * t1.x - t0.x * z1;
        float cz = t0.x * t1.y - t0.y * t1.x;
        float vol = (cx * t2.x + cy * t2.y + cz * z2) * (1.0f / 6.0f);
        #pragma unroll
        for (int q = 0; q < NPARTS; q++) accp[q] += (p == q) ? vol : 0.f;
    }

    // ---- Phase B-ovf: rare entries, global reads (L2-hot) ----
    const int nofF = counts[0];
    for (int k = tid; k < nofF; k += NTHREADS) {
        uint2 ft = ovf_f[k];
        int i0 = ft.x & 0xFFFF, i1 = ft.x >> 16;
        int i2 = ft.y & 0xFFFF, p  = (int)(ft.y >> 16);
        float x0 = vb[3*i0+0], y0 = vb[3*i0+1], z0 = vb[3*i0+2];
        float x1 = vb[3*i1+0], y1 = vb[3*i1+1], z1 = vb[3*i1+2];
        float x2 = vb[3*i2+0], y2 = vb[3*i2+1], z2 = vb[3*i2+2];
        float cx = y0 * z1 - z0 * y1;
        float cy = z0 * x1 - x0 * z1;
        float cz = x0 * y1 - y0 * x1;
        float vol = (cx * x2 + cy * y2 + cz * z2) * (1.0f / 6.0f);
        #pragma unroll
        for (int q = 0; q < NPARTS; q++) accp[q] += (p == q) ? vol : 0.f;
    }

    #pragma unroll
    for (int q = 0; q < NPARTS; q++) {
        float s = accp[q];
        #pragma unroll
        for (int off = 32; off > 0; off >>= 1) s += __shfl_down(s, off, 64);
        accp[q] = s;
    }
    if (lane == 0) {
        #pragma unroll
        for (int q = 0; q < NPARTS; q++) sredp[wave][q] = accp[q];
    }
    __syncthreads();
    if (tid < NPARTS) {
        float s = 0.f;
        #pragma unroll
        for (int w = 0; w < NWAVES; w++) s += sredp[w][tid];
        spart[tid] = s;
    }
    if (tid == NPARTS) spart[NPARTS] = 0.f;
    __syncthreads();

    // ---- Phase C: clean HD entries, pure-LDS, branch-free ----
    float sVx = 0.f, sVz = 0.f, sVol = 0.f;
    float sPx = 0.f, sPz = 0.f, sPw  = 0.f;

    #pragma unroll 2
    for (int v = tid; v < NVHD; v += NTHREADS) {
        uint4 hp = hd_pack[v];
        int i0 = hp.x & 0xFFFF, i1 = hp.x >> 16;
        int i2 = hp.y & 0xFFFF, p  = (int)(hp.y >> 16);
        float w0 = __uint_as_float(hp.z);
        float w1 = __uint_as_float(hp.w);
        float w2 = 1.0f - w0 - w1;
        float2 t0 = sxy[i0]; float z0 = szz[i0];
        float2 t1 = sxy[i1]; float z1 = szz[i1];
        float2 t2 = sxy[i2]; float z2 = szz[i2];
        float x = w0 * t0.x + w1 * t1.x + w2 * t2.x;
        float y = w0 * t0.y + w1 * t1.y + w2 * t2.y;
        float z = w0 * z0   + w1 * z1   + w2 * z2;
        float vol = spart[p];
        float pw  = (y < 0.f) ? fmaf(-100.f, y, 1.f) : __expf(-10.f * y);
        sVx += x * vol;  sVz += z * vol;  sVol += vol;
        sPx += x * pw;   sPz += z * pw;   sPw  += pw;
    }

    // ---- Phase C-ovf ----
    const int nofH = counts[1];
    for (int k = tid; k < nofH; k += NTHREADS) {
        uint4 hp = ovf_h[k];
        int i0 = hp.x & 0xFFFF, i1 = hp.x >> 16;
        int i2 = hp.y & 0xFFFF, p  = (int)(hp.y >> 16);
        float w0 = __uint_as_float(hp.z);
        float w1 = __uint_as_float(hp.w);
        float w2 = 1.0f - w0 - w1;
        float x0 = vb[3*i0+0], y0 = vb[3*i0+1], z0 = vb[3*i0+2];
        float x1 = vb[3*i1+0], y1 = vb[3*i1+1], z1 = vb[3*i1+2];
        float x2 = vb[3*i2+0], y2 = vb[3*i2+1], z2 = vb[3*i2+2];
        float x = w0 * x0 + w1 * x1 + w2 * x2;
        float y = w0 * y0 + w1 * y1 + w2 * y2;
        float z = w0 * z0 + w1 * z1 + w2 * z2;
        float vol = spart[p];
        float pw  = (y < 0.f) ? fmaf(-100.f, y, 1.f) : __expf(-10.f * y);
        sVx += x * vol;  sVz += z * vol;  sVol += vol;
        sPx += x * pw;   sPz += z * pw;   sPw  += pw;
    }

    float vals[6] = {sVx, sVz, sVol, sPx, sPz, sPw};
    #pragma unroll
    for (int q = 0; q < 6; q++) {
        float s = vals[q];
        #pragma unroll
        for (int off = 32; off > 0; off >>= 1) s += __shfl_down(s, off, 64);
        vals[q] = s;
    }
    float* sred6 = &sredp[0][0];   // reuse (dead after spart): 16*6*4 = 384 B
    if (lane == 0) {
        #pragma unroll
        for (int q = 0; q < 6; q++) sred6[wave * 6 + q] = vals[q];
    }
    __syncthreads();
    if (tid == 0) {
        float r[6];
        #pragma unroll
        for (int q = 0; q < 6; q++) {
            float s = 0.f;
            #pragma unroll
            for (int w = 0; w < NWAVES; w++) s += sred6[w * 6 + q];
            r[q] = s;
        }
        float invVol = 1.0f / r[2];
        float invPw  = 1.0f / (r[5] + 1e-6f);
        float comx = r[0] * invVol, comz = r[1] * invVol;
        float copx = r[3] * invPw,  copz = r[4] * invPw;
        float d0 = comx - copx, d2 = comz - copz;
        out[b] = sqrtf(d0 * d0 + d2 * d2);
    }
}

extern "C" void kernel_launch(void* const* d_in, const int* in_sizes, int n_in,
                              void* d_out, int out_size, void* d_ws, size_t ws_size,
                              hipStream_t stream) {
    const float* vertices = (const float*)d_in[0];
    const float* bary     = (const float*)d_in[1];
    const int*   faces    = (const int*)d_in[2];
    const int*   hd_fid   = (const int*)d_in[3];
    const int*   part_fid = (const int*)d_in[4];
    float* out = (float*)d_out;

    // ws layout (16B-aligned): f_pack | hd_pack | ovf_h | ovf_f | counts
    char* ws = (char*)d_ws;
    uint2* f_pack  = (uint2*)ws;                          // 110208
    uint4* hd_pack = (uint4*)(ws + 110208);               // 320000
    uint4* ovf_h   = (uint4*)(ws + 110208 + 320000);      // 320000 (worst case)
    uint2* ovf_f   = (uint2*)(ws + 110208 + 640000);      // 110208 (worst case)
    int*   counts  = (int*)(ws + 110208 + 640000 + 110208);

    build_tables<<<(NVHD + 255) / 256, 256, 0, stream>>>(bary, faces, hd_fid, part_fid,
                                                         f_pack, hd_pack);
    split_overflow<<<2, 1024, 0, stream>>>(f_pack, hd_pack, ovf_f, ovf_h, counts);
    stab_kernel<<<NB, NTHREADS, 0, stream>>>(vertices, f_pack, hd_pack, ovf_f, ovf_h, counts, out);
}